// Round 4
// baseline (401.695 us; speedup 1.0000x reference)
//
#include <hip/hip_runtime.h>
#include <hip/hip_bf16.h>

#define BATCH 4096

typedef __attribute__((ext_vector_type(8))) short short8;
typedef __attribute__((ext_vector_type(4))) short short4_t;
typedef __attribute__((ext_vector_type(4))) float f32x4;

#define MFMA_BF16 __builtin_amdgcn_mfma_f32_16x16x32_bf16

// light barrier: waits LDS ops only; global loads stay in flight across it
#define LBAR() asm volatile("s_waitcnt lgkmcnt(0)\n\ts_barrier" ::: "memory")

__device__ __forceinline__ float frelu(float v) { return v > 0.f ? v : 0.f; }
__device__ __forceinline__ unsigned short f2bf(float f) {
    return __builtin_bit_cast(unsigned short, __float2bfloat16(f));
}

// ---------------- prep: permute+cvt weights to bf16 K-contiguous layouts; init out ----------------
__global__ __launch_bounds__(256) void prep_kernel(const float* __restrict__ w1, const float* __restrict__ w2,
                                                   const float* __restrict__ w3, const float* __restrict__ w4,
                                                   const float* __restrict__ b5,
                                                   unsigned short* __restrict__ w1p, unsigned short* __restrict__ w2p,
                                                   unsigned short* __restrict__ w3p, unsigned short* __restrict__ w4p,
                                                   float* __restrict__ out) {
    int idx = blockIdx.x * 256 + threadIdx.x;
    if (idx < 6144) {
        w1p[idx] = f2bf(w1[idx]);
    } else if (idx < 24576) {
        int j = idx - 6144;
        int oc = j / 288, k = j % 288;
        int khw = k / 32, ic = k % 32;
        w2p[j] = f2bf(w2[oc * 288 + ic * 9 + khw]);
    } else if (idx < 61440) {
        int j = idx - 24576;
        int oc = j / 576, k = j % 576;
        int khw = k / 64, ic = k % 64;
        w3p[j] = f2bf(w3[oc * 576 + ic * 9 + khw]);
    } else if (idx < 552960) {
        int j = idx - 61440;
        int n = j / 960, k = j % 960;
        int pos = k / 64, oc = k % 64;
        w4p[j] = f2bf(w4[n * 960 + oc * 15 + pos]);
    } else if (idx < 561152) {
        int j = idx - 552960;
        out[j] = b5[j & 1];
    } else if (idx < 561367) {
        out[8192 + (idx - 561152)] = 0.f;
    }
}

// ---------------- fused conv1+conv2+conv3: 4 images per block, software-pipelined ----------------
// Per image: stage(ub) -> conv1(regs) -> epi(x2l overlays ub) -> conv2(x4l) -> conv3(x6l).
// Image i+1's global loads are issued into registers during image i's compute and stay in
// flight across the light barriers. x4l/x6l live OUTSIDE ub so staging never clobbers them.
__global__ __launch_bounds__(256, 4) void fused_convs(const float* __restrict__ x,
                                                      const unsigned short* __restrict__ w1p, const float* __restrict__ b1,
                                                      const unsigned short* __restrict__ w2p, const float* __restrict__ b2,
                                                      const unsigned short* __restrict__ w3p, const float* __restrict__ b3,
                                                      unsigned short* __restrict__ x6, float* __restrict__ redbuf) {
    constexpr int RS = 68;                                    // image row stride (shorts)
    __shared__ __align__(16) unsigned short ub[3 * 48 * RS];  // 19,584 B: image, then x2l overlay
    __shared__ __align__(16) unsigned short x4l[35 * 72];     //  5,040 B
    __shared__ __align__(16) unsigned short x6l[15 * 64];     //  1,920 B
    __shared__ float red[215];                                // ave1|ave2|ave3 partials
    unsigned short* x2l = ub;                                 // [165][36]

    const int tid = threadIdx.x;
    const int wave = tid >> 6, lane = tid & 63;
    const int col = lane & 15, quad = lane >> 4;
    const int img0 = blockIdx.x * 4;

    const float bias0 = b1[col], bias1 = b1[col + 16];

    float4 pf[9];
    {
        const float4* xs = (const float4*)(x + (size_t)img0 * 9216);
        #pragma unroll
        for (int i = 0; i < 9; ++i) pf[i] = xs[tid + i * 256];
    }

    for (int it = 0; it < 4; ++it) {
        const int img = img0 + it;

        // ---- S phase: export prev image's x6/red, zero red, stage ub, issue next prefetch ----
        if (it > 0) {
            if (tid < 120) ((float4*)(x6 + (size_t)(img - 1) * 960))[tid] = ((const float4*)x6l)[tid];
            if (tid < 215) redbuf[(size_t)(img - 1) * 216 + tid] = red[tid];
        }
        if (tid < 215) red[tid] = 0.f;
        #pragma unroll
        for (int i = 0; i < 9; ++i) {
            const int idx = tid + i * 256;             // float4 index 0..2303
            const int r = idx >> 4, cf = (idx & 15) * 4;
            float4 v = pf[i];
            short4_t s;
            s[0] = (short)f2bf(v.x); s[1] = (short)f2bf(v.y);
            s[2] = (short)f2bf(v.z); s[3] = (short)f2bf(v.w);
            *(short4_t*)(ub + r * RS + cf) = s;
        }
        if (it < 3) {                                  // prefetch next image; in flight across barriers
            const float4* xs = (const float4*)(x + (size_t)(img + 1) * 9216);
            #pragma unroll
            for (int i = 0; i < 9; ++i) pf[i] = xs[tid + i * 256];
        }
        LBAR();

        // ---- conv1: 11 m-tiles over 4 waves, N=32, K=192 (6 chunks); accs in regs ----
        f32x4 c1a[3][2] = {};
        const unsigned short* w1b0 = w1p + (size_t)col * 192 + quad * 8;
        const unsigned short* w1b1 = w1b0 + 16 * 192;
        #pragma unroll
        for (int ti = 0; ti < 3; ++ti) {
            const int t = wave + ti * 4;
            if (t >= 11) break;
            const int posA = t * 16 + col;
            const int pm = posA < 165 ? posA : 164;
            const int oh = pm / 15, ow = pm % 15;
            #pragma unroll
            for (int c = 0; c < 6; ++c) {
                const int ic = c >> 1;
                const int kh = (c & 1) * 4 + quad;
                const unsigned short* ap = ub + (ic * 48 + oh * 4 + kh) * RS + ow * 4;
                short8 af;
                *(short4_t*)&af       = *(const short4_t*)ap;
                *((short4_t*)&af + 1) = *(const short4_t*)(ap + 4);
                short8 B0 = *(const short8*)(w1b0 + c * 32);
                short8 B1 = *(const short8*)(w1b1 + c * 32);
                c1a[ti][0] = MFMA_BF16(af, B0, c1a[ti][0], 0, 0, 0);
                c1a[ti][1] = MFMA_BF16(af, B1, c1a[ti][1], 0, 0, 0);
            }
        }
        LBAR();   // all image reads done -> x2l may overlay ub

        // ---- conv1 epilogue: bias/relu -> x2l; ave1 partials ----
        #pragma unroll
        for (int ti = 0; ti < 3; ++ti) {
            const int t = wave + ti * 4;
            if (t >= 11) break;
            #pragma unroll
            for (int r = 0; r < 4; ++r) {
                const int pr = t * 16 + quad * 4 + r;
                float v0 = c1a[ti][0][r] + bias0;
                float v1 = c1a[ti][1][r] + bias1;
                float s = v0 + v1;
                s += __shfl_xor(s, 1); s += __shfl_xor(s, 2);
                s += __shfl_xor(s, 4); s += __shfl_xor(s, 8);
                if (pr < 165) {
                    if (col == 0) atomicAdd(&red[pr], s);
                    x2l[pr * 36 + col]      = f2bf(frelu(v0));
                    x2l[pr * 36 + col + 16] = f2bf(frelu(v1));
                }
            }
        }
        LBAR();

        // ---- conv2: M=35 (3 m-tiles), wave owns 16-oc n-slice, K=288 (9 chunks) ----
        {
            const int oc2 = wave * 16 + col;
            const unsigned short* w2b = w2p + (size_t)oc2 * 288 + quad * 8;
            int aoff[3];
            #pragma unroll
            for (int mt = 0; mt < 3; ++mt) {
                int p = mt * 16 + col; p = p < 35 ? p : 34;
                aoff[mt] = ((p / 7) * 30 + (p % 7) * 2) * 36 + quad * 8;
            }
            f32x4 a2[3] = {};
            #pragma unroll
            for (int c = 0; c < 9; ++c) {
                short8 Bc = *(const short8*)(w2b + c * 32);
                const int koff = ((c / 3) * 15 + (c % 3)) * 36;
                #pragma unroll
                for (int mt = 0; mt < 3; ++mt) {
                    const unsigned short* ap = x2l + aoff[mt] + koff;
                    short8 af;
                    *(short4_t*)&af       = *(const short4_t*)ap;
                    *((short4_t*)&af + 1) = *(const short4_t*)(ap + 4);
                    a2[mt] = MFMA_BF16(af, Bc, a2[mt], 0, 0, 0);
                }
            }
            const float bv2 = b2[oc2];
            #pragma unroll
            for (int mt = 0; mt < 3; ++mt) {
                #pragma unroll
                for (int r = 0; r < 4; ++r) {
                    const int pr = mt * 16 + quad * 4 + r;
                    float v = a2[mt][r] + bv2;
                    float s = v;
                    s += __shfl_xor(s, 1); s += __shfl_xor(s, 2);
                    s += __shfl_xor(s, 4); s += __shfl_xor(s, 8);
                    if (pr < 35) {
                        x4l[pr * 72 + oc2] = f2bf(frelu(v));
                        if (col == 0) atomicAdd(&red[165 + pr], s);
                    }
                }
            }
        }
        LBAR();

        // ---- conv3: M=15, wave owns 16-oc n-slice, K=576 (18 chunks, dual chains) ----
        {
            const int oc3 = wave * 16 + col;
            const unsigned short* w3b = w3p + (size_t)oc3 * 576 + quad * 8;
            int p = col < 15 ? col : 14;
            const int abase = ((p / 5) * 7 + (p % 5)) * 72;
            f32x4 aA = {}, aB = {};
            #pragma unroll
            for (int cc = 0; cc < 9; ++cc) {
                const int kh = cc / 3, kw = cc % 3;
                const unsigned short* bp = x4l + abase + (kh * 7 + kw) * 72 + quad * 8;
                short8 af0 = *(const short8*)bp;          // ic 0..31  (16B aligned)
                short8 af1 = *(const short8*)(bp + 32);   // ic 32..63
                short8 B0 = *(const short8*)(w3b + (2 * cc) * 32);
                short8 B1 = *(const short8*)(w3b + (2 * cc + 1) * 32);
                aA = MFMA_BF16(af0, B0, aA, 0, 0, 0);
                aB = MFMA_BF16(af1, B1, aB, 0, 0, 0);
            }
            f32x4 a3 = aA + aB;
            const float bv3 = b3[oc3];
            #pragma unroll
            for (int r = 0; r < 4; ++r) {
                const int pr = quad * 4 + r;
                float v = a3[r] + bv3;
                float s = v;
                s += __shfl_xor(s, 1); s += __shfl_xor(s, 2);
                s += __shfl_xor(s, 4); s += __shfl_xor(s, 8);
                if (pr < 15) {
                    x6l[pr * 64 + oc3] = f2bf(frelu(v));
                    if (col == 0) atomicAdd(&red[200 + pr], s);
                }
            }
        }
        LBAR();   // x6l/red complete for this image
    }

    // epilogue: export last image
    if (tid < 120) ((float4*)(x6 + (size_t)(img0 + 3) * 960))[tid] = ((const float4*)x6l)[tid];
    if (tid < 215) redbuf[(size_t)(img0 + 3) * 216 + tid] = red[tid];
}

// ---------------- reduce: out[8192+row] = sum_img redbuf[img][row] * scale ----------------
__global__ __launch_bounds__(256) void reduce_aves(const float* __restrict__ redbuf, float* __restrict__ out) {
    const int row = blockIdx.x;
    float s = 0.f;
    for (int i = threadIdx.x; i < 4096; i += 256) s += redbuf[(size_t)i * 216 + row];
    s += __shfl_down(s, 32); s += __shfl_down(s, 16); s += __shfl_down(s, 8);
    s += __shfl_down(s, 4);  s += __shfl_down(s, 2);  s += __shfl_down(s, 1);
    __shared__ float wsum[4];
    if ((threadIdx.x & 63) == 0) wsum[threadIdx.x >> 6] = s;
    __syncthreads();
    if (threadIdx.x == 0)
        out[8192 + row] = (wsum[0] + wsum[1] + wsum[2] + wsum[3]) * (row < 165 ? 0.03125f : 0.015625f);
}

// ---------------- fc4+fc5: out[b,2] += relu(x6@w4p^T + b4) @ w5^T ----------------
__global__ __launch_bounds__(256) void fc45_mfma(const unsigned short* __restrict__ x6,
                                                 const unsigned short* __restrict__ w4p, const float* __restrict__ b4,
                                                 const float* __restrict__ w5, float* __restrict__ out) {
    __shared__ float outl[32][2];
    const int tid = threadIdx.x;
    const int wave = tid >> 6, lane = tid & 63;
    const int col = lane & 15, quad = lane >> 4;
    if (tid < 64) outl[tid >> 1][tid & 1] = 0.f;
    const int m0 = blockIdx.x * 32;
    const int oc = blockIdx.y * 64 + wave * 16 + col;

    const unsigned short* brow  = w4p + (size_t)oc * 960 + quad * 8;
    const unsigned short* arow0 = x6 + (size_t)(m0 + col) * 960 + quad * 8;
    const unsigned short* arow1 = arow0 + 16 * 960;
    f32x4 acc0 = {}, acc1 = {};
    __syncthreads();
    #pragma unroll 6
    for (int c = 0; c < 30; ++c) {
        short8 Bf = *(const short8*)(brow + c * 32);
        short8 a0 = *(const short8*)(arow0 + c * 32);
        short8 a1 = *(const short8*)(arow1 + c * 32);
        acc0 = MFMA_BF16(a0, Bf, acc0, 0, 0, 0);
        acc1 = MFMA_BF16(a1, Bf, acc1, 0, 0, 0);
    }
    const float bb = b4[oc], u0 = w5[oc], u1 = w5[512 + oc];
    #pragma unroll
    for (int mi = 0; mi < 2; ++mi) {
        const f32x4 acc = mi ? acc1 : acc0;
        #pragma unroll
        for (int r = 0; r < 4; ++r) {
            float h = frelu(acc[r] + bb);
            float l0 = h * u0, l1 = h * u1;
            l0 += __shfl_xor(l0, 1); l0 += __shfl_xor(l0, 2); l0 += __shfl_xor(l0, 4); l0 += __shfl_xor(l0, 8);
            l1 += __shfl_xor(l1, 1); l1 += __shfl_xor(l1, 2); l1 += __shfl_xor(l1, 4); l1 += __shfl_xor(l1, 8);
            if (col == 0) {
                atomicAdd(&outl[mi * 16 + quad * 4 + r][0], l0);
                atomicAdd(&outl[mi * 16 + quad * 4 + r][1], l1);
            }
        }
    }
    __syncthreads();
    if (tid < 64) atomicAdd(&out[(m0 + (tid >> 1)) * 2 + (tid & 1)], outl[tid >> 1][tid & 1]);
}

extern "C" void kernel_launch(void* const* d_in, const int* in_sizes, int n_in,
                              void* d_out, int out_size, void* d_ws, size_t ws_size,
                              hipStream_t stream) {
    const float* x  = (const float*)d_in[0];
    const float* w1 = (const float*)d_in[1];
    const float* b1 = (const float*)d_in[2];
    const float* w2 = (const float*)d_in[3];
    const float* b2 = (const float*)d_in[4];
    const float* w3 = (const float*)d_in[5];
    const float* b3 = (const float*)d_in[6];
    const float* w4 = (const float*)d_in[7];
    const float* b4 = (const float*)d_in[8];
    const float* w5 = (const float*)d_in[9];
    const float* b5 = (const float*)d_in[10];
    float* out = (float*)d_out;

    unsigned short* ws = (unsigned short*)d_ws;
    unsigned short* x6  = ws;                      // 3,932,160 ushort
    unsigned short* w1p = ws + 3932160;            //      6,144
    unsigned short* w2p = ws + 3938304;            //     18,432
    unsigned short* w3p = ws + 3956736;            //     36,864
    unsigned short* w4p = ws + 3993600;            //    491,520
    float* redbuf = (float*)((char*)d_ws + 8970240); // 4096*216 floats

    prep_kernel<<<2193, 256, 0, stream>>>(w1, w2, w3, w4, b5, w1p, w2p, w3p, w4p, out);
    fused_convs<<<1024, 256, 0, stream>>>(x, w1p, b1, w2p, b2, w3p, b3, x6, redbuf);
    reduce_aves<<<215, 256, 0, stream>>>(redbuf, out);
    fc45_mfma<<<dim3(128, 8), 256, 0, stream>>>(x6, w4p, b4, w5, out);
}

// Round 5
// 340.977 us; speedup vs baseline: 1.1781x; 1.1781x over previous
//
#include <hip/hip_runtime.h>
#include <hip/hip_bf16.h>

#define BATCH 4096

typedef __attribute__((ext_vector_type(8))) short short8;
typedef __attribute__((ext_vector_type(4))) short short4_t;
typedef __attribute__((ext_vector_type(4))) float f32x4;

#define MFMA_BF16 __builtin_amdgcn_mfma_f32_16x16x32_bf16

// wave-local LDS drain (no barrier!): all this wave's LDS ops complete
#define WWAIT() asm volatile("s_waitcnt lgkmcnt(0)" ::: "memory")

__device__ __forceinline__ float frelu(float v) { return v > 0.f ? v : 0.f; }
__device__ __forceinline__ unsigned short f2bf(float f) {
    return __builtin_bit_cast(unsigned short, __float2bfloat16(f));
}

// ---------------- prep: permute+cvt weights to bf16 K-contiguous layouts; init out ----------------
__global__ __launch_bounds__(256) void prep_kernel(const float* __restrict__ w1, const float* __restrict__ w2,
                                                   const float* __restrict__ w3, const float* __restrict__ w4,
                                                   const float* __restrict__ b5,
                                                   unsigned short* __restrict__ w1p, unsigned short* __restrict__ w2p,
                                                   unsigned short* __restrict__ w3p, unsigned short* __restrict__ w4p,
                                                   float* __restrict__ out) {
    int idx = blockIdx.x * 256 + threadIdx.x;
    if (idx < 6144) {
        w1p[idx] = f2bf(w1[idx]);
    } else if (idx < 24576) {
        int j = idx - 6144;
        int oc = j / 288, k = j % 288;
        int khw = k / 32, ic = k % 32;
        w2p[j] = f2bf(w2[oc * 288 + ic * 9 + khw]);
    } else if (idx < 61440) {
        int j = idx - 24576;
        int oc = j / 576, k = j % 576;
        int khw = k / 64, ic = k % 64;
        w3p[j] = f2bf(w3[oc * 576 + ic * 9 + khw]);
    } else if (idx < 552960) {
        int j = idx - 61440;
        int n = j / 960, k = j % 960;
        int pos = k / 64, oc = k % 64;
        w4p[j] = f2bf(w4[n * 960 + oc * 15 + pos]);
    } else if (idx < 561152) {
        int j = idx - 552960;
        out[j] = b5[j & 1];
    } else if (idx < 561367) {
        out[8192 + (idx - 561152)] = 0.f;
    }
}

// ---------------- fused convs: ONE IMAGE PER WAVE, zero barriers ----------------
// Each wave owns a private 19,584B LDS slab: ub=[144][68] image (bf16), x2l=[165][36]
// overlays ub after conv1 (accs held in regs), x4l=[35][72] at +5952. conv2/conv3 compute
// all 64 oc in-wave (4 n-tiles). ave partials -> redbuf direct (one writer per slot, no atomics).
__global__ __launch_bounds__(256, 2) void fused_convs(const float* __restrict__ x,
                                                      const unsigned short* __restrict__ w1p, const float* __restrict__ b1,
                                                      const unsigned short* __restrict__ w2p, const float* __restrict__ b2,
                                                      const unsigned short* __restrict__ w3p, const float* __restrict__ b3,
                                                      unsigned short* __restrict__ x6, float* __restrict__ redbuf) {
    __shared__ __align__(16) unsigned short S[4][9792];   // 78,336 B -> 2 blocks/CU
    const int tid = threadIdx.x;
    const int wave = tid >> 6, lane = tid & 63;
    const int col = lane & 15, quad = lane >> 4;
    const int img = blockIdx.x * 4 + wave;

    unsigned short* ub  = S[wave];          // [144][68] image rows (row = ic*48 + h)
    unsigned short* x2l = ub;               // [165][36] overlays ub after conv1
    unsigned short* x4l = ub + 5952;        // [35][72]  (byte 11904, 16B aligned)
    float* redrow = redbuf + (size_t)img * 216;

    // ---- stage image (wave-private): 2304 float4 / 64 lanes = 36 each, 3 batches of 12 ----
    {
        const float4* xs = (const float4*)(x + (size_t)img * 9216);
        #pragma unroll
        for (int b = 0; b < 3; ++b) {
            float4 t[12];
            #pragma unroll
            for (int i = 0; i < 12; ++i) t[i] = xs[lane + (b * 12 + i) * 64];
            #pragma unroll
            for (int i = 0; i < 12; ++i) {
                const int idx = lane + (b * 12 + i) * 64;
                const int r = idx >> 4, cf = (idx & 15) * 4;
                short4_t s;
                s[0] = (short)f2bf(t[i].x); s[1] = (short)f2bf(t[i].y);
                s[2] = (short)f2bf(t[i].z); s[3] = (short)f2bf(t[i].w);
                *(short4_t*)(ub + r * 68 + cf) = s;
            }
        }
    }
    WWAIT();

    // ---- conv1: 11 m-tiles, N=32 (2 n-tiles), K=192 (6 chunks); ALL accs held in regs ----
    short8 Bf1[2][6];
    #pragma unroll
    for (int nt = 0; nt < 2; ++nt) {
        const unsigned short* wb = w1p + (size_t)(nt * 16 + col) * 192 + quad * 8;
        #pragma unroll
        for (int c = 0; c < 6; ++c) Bf1[nt][c] = *(const short8*)(wb + c * 32);
    }
    f32x4 c1a[11][2] = {};
    #pragma unroll
    for (int t = 0; t < 11; ++t) {
        const int posA = t * 16 + col;
        const int pm = posA < 165 ? posA : 164;
        const int oh = pm / 15, ow = pm % 15;
        #pragma unroll
        for (int c = 0; c < 6; ++c) {
            const int ic = c >> 1;
            const int kh = (c & 1) * 4 + quad;
            const unsigned short* ap = ub + (ic * 48 + oh * 4 + kh) * 68 + ow * 4;
            short8 af;
            *(short4_t*)&af       = *(const short4_t*)ap;
            *((short4_t*)&af + 1) = *(const short4_t*)(ap + 4);
            c1a[t][0] = MFMA_BF16(af, Bf1[0][c], c1a[t][0], 0, 0, 0);
            c1a[t][1] = MFMA_BF16(af, Bf1[1][c], c1a[t][1], 0, 0, 0);
        }
    }
    WWAIT();   // all image reads done -> x2l may overlay ub (wave-private, no barrier)

    // ---- conv1 epilogue: bias/relu -> x2l; ave1 -> redbuf rows 0..164 (direct, 1 writer) ----
    {
        const float bias0 = b1[col], bias1 = b1[col + 16];
        #pragma unroll
        for (int t = 0; t < 11; ++t) {
            #pragma unroll
            for (int r = 0; r < 4; ++r) {
                const int pr = t * 16 + quad * 4 + r;
                float v0 = c1a[t][0][r] + bias0;
                float v1 = c1a[t][1][r] + bias1;
                float s = v0 + v1;
                s += __shfl_xor(s, 1); s += __shfl_xor(s, 2);
                s += __shfl_xor(s, 4); s += __shfl_xor(s, 8);
                if (pr < 165) {
                    x2l[pr * 36 + col]      = f2bf(frelu(v0));
                    x2l[pr * 36 + col + 16] = f2bf(frelu(v1));
                    if (col == 0) redrow[pr] = s;
                }
            }
        }
    }
    WWAIT();

    // ---- conv2: M=35 (3 m-tiles), N=64 (4 n-tiles in-wave), K=288 (9 chunks) ----
    {
        int aoff[3];
        #pragma unroll
        for (int mt = 0; mt < 3; ++mt) {
            int p = mt * 16 + col; p = p < 35 ? p : 34;
            aoff[mt] = ((p / 7) * 30 + (p % 7) * 2) * 36 + quad * 8;
        }
        f32x4 a2[3][4] = {};
        #pragma unroll
        for (int c = 0; c < 9; ++c) {
            const int koff = ((c / 3) * 15 + (c % 3)) * 36;
            short8 A[3];
            #pragma unroll
            for (int mt = 0; mt < 3; ++mt) {
                const unsigned short* ap = x2l + aoff[mt] + koff;
                *(short4_t*)&A[mt]       = *(const short4_t*)ap;
                *((short4_t*)&A[mt] + 1) = *(const short4_t*)(ap + 4);
            }
            #pragma unroll
            for (int nt = 0; nt < 4; ++nt) {
                short8 Bc = *(const short8*)(w2p + (size_t)(nt * 16 + col) * 288 + c * 32 + quad * 8);
                #pragma unroll
                for (int mt = 0; mt < 3; ++mt)
                    a2[mt][nt] = MFMA_BF16(A[mt], Bc, a2[mt][nt], 0, 0, 0);
            }
        }
        float bv2[4];
        #pragma unroll
        for (int nt = 0; nt < 4; ++nt) bv2[nt] = b2[nt * 16 + col];
        #pragma unroll
        for (int mt = 0; mt < 3; ++mt) {
            #pragma unroll
            for (int r = 0; r < 4; ++r) {
                const int pr = mt * 16 + quad * 4 + r;
                if (pr < 35) {
                    float s = 0.f;
                    #pragma unroll
                    for (int nt = 0; nt < 4; ++nt) {
                        float v = a2[mt][nt][r] + bv2[nt];
                        s += v;
                        x4l[pr * 72 + nt * 16 + col] = f2bf(frelu(v));
                    }
                    s += __shfl_xor(s, 1); s += __shfl_xor(s, 2);
                    s += __shfl_xor(s, 4); s += __shfl_xor(s, 8);
                    if (col == 0) redrow[165 + pr] = s;
                }
            }
        }
    }
    WWAIT();

    // ---- conv3: M=15 (1 tile), N=64 (4 n-tiles in-wave), K=576 (18 chunks, dual per cc) ----
    {
        int p = col < 15 ? col : 14;
        const int abase = ((p / 5) * 7 + (p % 5)) * 72;
        f32x4 a3[4] = {};
        #pragma unroll
        for (int cc = 0; cc < 9; ++cc) {
            const unsigned short* bp = x4l + abase + ((cc / 3) * 7 + (cc % 3)) * 72 + quad * 8;
            short8 af0 = *(const short8*)bp;          // ic 0..31  (16B aligned)
            short8 af1 = *(const short8*)(bp + 32);   // ic 32..63
            #pragma unroll
            for (int nt = 0; nt < 4; ++nt) {
                const unsigned short* wb = w3p + (size_t)(nt * 16 + col) * 576 + quad * 8;
                short8 B0 = *(const short8*)(wb + (2 * cc) * 32);
                short8 B1 = *(const short8*)(wb + (2 * cc + 1) * 32);
                a3[nt] = MFMA_BF16(af0, B0, a3[nt], 0, 0, 0);
                a3[nt] = MFMA_BF16(af1, B1, a3[nt], 0, 0, 0);
            }
        }
        float bv3[4];
        #pragma unroll
        for (int nt = 0; nt < 4; ++nt) bv3[nt] = b3[nt * 16 + col];
        unsigned short* xout = x6 + (size_t)img * 960;
        #pragma unroll
        for (int r = 0; r < 4; ++r) {
            const int pr = quad * 4 + r;
            if (pr < 15) {
                float s = 0.f;
                #pragma unroll
                for (int nt = 0; nt < 4; ++nt) {
                    float v = a3[nt][r] + bv3[nt];
                    s += v;
                    xout[pr * 64 + nt * 16 + col] = f2bf(frelu(v));
                }
                s += __shfl_xor(s, 1); s += __shfl_xor(s, 2);
                s += __shfl_xor(s, 4); s += __shfl_xor(s, 8);
                if (col == 0) redrow[200 + pr] = s;
            }
        }
    }
}

// ---------------- reduce: out[8192+row] = sum_img redbuf[img][row] * scale ----------------
__global__ __launch_bounds__(256) void reduce_aves(const float* __restrict__ redbuf, float* __restrict__ out) {
    const int row = blockIdx.x;
    float s = 0.f;
    for (int i = threadIdx.x; i < 4096; i += 256) s += redbuf[(size_t)i * 216 + row];
    s += __shfl_down(s, 32); s += __shfl_down(s, 16); s += __shfl_down(s, 8);
    s += __shfl_down(s, 4);  s += __shfl_down(s, 2);  s += __shfl_down(s, 1);
    __shared__ float wsum[4];
    if ((threadIdx.x & 63) == 0) wsum[threadIdx.x >> 6] = s;
    __syncthreads();
    if (threadIdx.x == 0)
        out[8192 + row] = (wsum[0] + wsum[1] + wsum[2] + wsum[3]) * (row < 165 ? 0.03125f : 0.015625f);
}

// ---------------- fc4+fc5: out[b,2] += relu(x6@w4p^T + b4) @ w5^T ----------------
__global__ __launch_bounds__(256) void fc45_mfma(const unsigned short* __restrict__ x6,
                                                 const unsigned short* __restrict__ w4p, const float* __restrict__ b4,
                                                 const float* __restrict__ w5, float* __restrict__ out) {
    __shared__ float outl[32][2];
    const int tid = threadIdx.x;
    const int wave = tid >> 6, lane = tid & 63;
    const int col = lane & 15, quad = lane >> 4;
    if (tid < 64) outl[tid >> 1][tid & 1] = 0.f;
    const int m0 = blockIdx.x * 32;
    const int oc = blockIdx.y * 64 + wave * 16 + col;

    const unsigned short* brow  = w4p + (size_t)oc * 960 + quad * 8;
    const unsigned short* arow0 = x6 + (size_t)(m0 + col) * 960 + quad * 8;
    const unsigned short* arow1 = arow0 + 16 * 960;
    f32x4 acc0 = {}, acc1 = {};
    __syncthreads();
    #pragma unroll 6
    for (int c = 0; c < 30; ++c) {
        short8 Bf = *(const short8*)(brow + c * 32);
        short8 a0 = *(const short8*)(arow0 + c * 32);
        short8 a1 = *(const short8*)(arow1 + c * 32);
        acc0 = MFMA_BF16(a0, Bf, acc0, 0, 0, 0);
        acc1 = MFMA_BF16(a1, Bf, acc1, 0, 0, 0);
    }
    const float bb = b4[oc], u0 = w5[oc], u1 = w5[512 + oc];
    #pragma unroll
    for (int mi = 0; mi < 2; ++mi) {
        const f32x4 acc = mi ? acc1 : acc0;
        #pragma unroll
        for (int r = 0; r < 4; ++r) {
            float h = frelu(acc[r] + bb);
            float l0 = h * u0, l1 = h * u1;
            l0 += __shfl_xor(l0, 1); l0 += __shfl_xor(l0, 2); l0 += __shfl_xor(l0, 4); l0 += __shfl_xor(l0, 8);
            l1 += __shfl_xor(l1, 1); l1 += __shfl_xor(l1, 2); l1 += __shfl_xor(l1, 4); l1 += __shfl_xor(l1, 8);
            if (col == 0) {
                atomicAdd(&outl[mi * 16 + quad * 4 + r][0], l0);
                atomicAdd(&outl[mi * 16 + quad * 4 + r][1], l1);
            }
        }
    }
    __syncthreads();
    if (tid < 64) atomicAdd(&out[(m0 + (tid >> 1)) * 2 + (tid & 1)], outl[tid >> 1][tid & 1]);
}

extern "C" void kernel_launch(void* const* d_in, const int* in_sizes, int n_in,
                              void* d_out, int out_size, void* d_ws, size_t ws_size,
                              hipStream_t stream) {
    const float* x  = (const float*)d_in[0];
    const float* w1 = (const float*)d_in[1];
    const float* b1 = (const float*)d_in[2];
    const float* w2 = (const float*)d_in[3];
    const float* b2 = (const float*)d_in[4];
    const float* w3 = (const float*)d_in[5];
    const float* b3 = (const float*)d_in[6];
    const float* w4 = (const float*)d_in[7];
    const float* b4 = (const float*)d_in[8];
    const float* w5 = (const float*)d_in[9];
    const float* b5 = (const float*)d_in[10];
    float* out = (float*)d_out;

    unsigned short* ws = (unsigned short*)d_ws;
    unsigned short* x6  = ws;                      // 3,932,160 ushort
    unsigned short* w1p = ws + 3932160;            //      6,144
    unsigned short* w2p = ws + 3938304;            //     18,432
    unsigned short* w3p = ws + 3956736;            //     36,864
    unsigned short* w4p = ws + 3993600;            //    491,520
    float* redbuf = (float*)((char*)d_ws + 8970240); // 4096*216 floats

    prep_kernel<<<2193, 256, 0, stream>>>(w1, w2, w3, w4, b5, w1p, w2p, w3p, w4p, out);
    fused_convs<<<1024, 256, 0, stream>>>(x, w1p, b1, w2p, b2, w3p, b3, x6, redbuf);
    reduce_aves<<<215, 256, 0, stream>>>(redbuf, out);
    fc45_mfma<<<dim3(128, 8), 256, 0, stream>>>(x6, w4p, b4, w5, out);
}

// Round 6
// 328.229 us; speedup vs baseline: 1.2238x; 1.0388x over previous
//
#include <hip/hip_runtime.h>
#include <hip/hip_bf16.h>

#define BATCH 4096

typedef __attribute__((ext_vector_type(8))) short short8;
typedef __attribute__((ext_vector_type(4))) short short4_t;
typedef __attribute__((ext_vector_type(4))) float f32x4;

#define MFMA_BF16 __builtin_amdgcn_mfma_f32_16x16x32_bf16

// light barrier: drains LDS ops then block-barrier; global loads stay in flight
#define LBAR() asm volatile("s_waitcnt lgkmcnt(0)\n\ts_barrier" ::: "memory")

__device__ __forceinline__ float frelu(float v) { return v > 0.f ? v : 0.f; }
__device__ __forceinline__ unsigned short f2bf(float f) {
    return __builtin_bit_cast(unsigned short, __float2bfloat16(f));
}

// ---------------- prep: permute+cvt weights to bf16 K-contiguous layouts; init out ----------------
__global__ __launch_bounds__(256) void prep_kernel(const float* __restrict__ w1, const float* __restrict__ w2,
                                                   const float* __restrict__ w3, const float* __restrict__ w4,
                                                   const float* __restrict__ b5,
                                                   unsigned short* __restrict__ w1p, unsigned short* __restrict__ w2p,
                                                   unsigned short* __restrict__ w3p, unsigned short* __restrict__ w4p,
                                                   float* __restrict__ out) {
    int idx = blockIdx.x * 256 + threadIdx.x;
    if (idx < 6144) {
        w1p[idx] = f2bf(w1[idx]);
    } else if (idx < 24576) {
        int j = idx - 6144;
        int oc = j / 288, k = j % 288;
        int khw = k / 32, ic = k % 32;
        w2p[j] = f2bf(w2[oc * 288 + ic * 9 + khw]);
    } else if (idx < 61440) {
        int j = idx - 24576;
        int oc = j / 576, k = j % 576;
        int khw = k / 64, ic = k % 64;
        w3p[j] = f2bf(w3[oc * 576 + ic * 9 + khw]);
    } else if (idx < 552960) {
        int j = idx - 61440;
        int n = j / 960, k = j % 960;
        int pos = k / 64, oc = k % 64;
        w4p[j] = f2bf(w4[n * 960 + oc * 15 + pos]);
    } else if (idx < 561152) {
        int j = idx - 552960;
        out[j] = b5[j & 1];
    } else if (idx < 561367) {
        out[8192 + (idx - 561152)] = 0.f;
    }
}

// ---------------- fused convs: TWO WAVES PER IMAGE, light barriers ----------------
// Block = 4 waves = 2 images. Wave pair (p=0,1) shares a 19,584B slab:
// ub=[144][68] image bf16; x2l=[165][36] overlays ub after conv1; x4l=[35][72] at +5952.
// conv1 m-tiles split by parity; conv2/conv3 split by 32-oc halves -> each wave loads only
// HALF the conv2/conv3 weights. Ave partials -> per-wave virtual redbuf row (8192 rows, no atomics).
__global__ __launch_bounds__(256) void fused_convs(const float* __restrict__ x,
                                                   const unsigned short* __restrict__ w1p, const float* __restrict__ b1,
                                                   const unsigned short* __restrict__ w2p, const float* __restrict__ b2,
                                                   const unsigned short* __restrict__ w3p, const float* __restrict__ b3,
                                                   unsigned short* __restrict__ x6, float* __restrict__ redbuf) {
    __shared__ __align__(16) unsigned short S[2][9792];   // 39,168 B -> 4 blocks/CU
    const int tid = threadIdx.x;
    const int wave = tid >> 6, lane = tid & 63;
    const int col = lane & 15, quad = lane >> 4;
    const int p = wave & 1;                               // oc-half / tile-parity
    const int img = blockIdx.x * 2 + (wave >> 1);

    unsigned short* ub  = S[wave >> 1];     // [144][68] image rows (row = ic*48 + h)
    unsigned short* x2l = ub;               // [165][36] overlays ub after conv1
    unsigned short* x4l = ub + 5952;        // [35][72]  (byte 11904, 16B aligned)
    float* vrow = redbuf + ((size_t)img * 2 + p) * 216;   // this wave's virtual partial row

    // ---- stage image: pair splits 2304 float4; 18 per lane in 2 batches of 9 ----
    {
        const float4* xs = (const float4*)(x + (size_t)img * 9216);
        #pragma unroll
        for (int b = 0; b < 2; ++b) {
            float4 t[9];
            #pragma unroll
            for (int i = 0; i < 9; ++i) t[i] = xs[(b * 9 + i) * 128 + p * 64 + lane];
            #pragma unroll
            for (int i = 0; i < 9; ++i) {
                const int idx = (b * 9 + i) * 128 + p * 64 + lane;
                const int r = idx >> 4, cf = (idx & 15) * 4;
                short4_t s;
                s[0] = (short)f2bf(t[i].x); s[1] = (short)f2bf(t[i].y);
                s[2] = (short)f2bf(t[i].z); s[3] = (short)f2bf(t[i].w);
                *(short4_t*)(ub + r * 68 + cf) = s;
            }
        }
    }
    LBAR();

    // ---- conv1: tiles t = 2*ti+p (A:6, B:5), N=32, K=192 (6 chunks); accs in regs ----
    short8 Bf1[2][6];
    #pragma unroll
    for (int nt = 0; nt < 2; ++nt) {
        const unsigned short* wb = w1p + (size_t)(nt * 16 + col) * 192 + quad * 8;
        #pragma unroll
        for (int c = 0; c < 6; ++c) Bf1[nt][c] = *(const short8*)(wb + c * 32);
    }
    f32x4 c1a[6][2] = {};
    #pragma unroll
    for (int ti = 0; ti < 6; ++ti) {
        const int t = ti * 2 + p;
        if (t >= 11) break;
        const int posA = t * 16 + col;
        const int pm = posA < 165 ? posA : 164;
        const int oh = pm / 15, ow = pm % 15;
        #pragma unroll
        for (int c = 0; c < 6; ++c) {
            const int ic = c >> 1;
            const int kh = (c & 1) * 4 + quad;
            const unsigned short* ap = ub + (ic * 48 + oh * 4 + kh) * 68 + ow * 4;
            short8 af;
            *(short4_t*)&af       = *(const short4_t*)ap;
            *((short4_t*)&af + 1) = *(const short4_t*)(ap + 4);
            c1a[ti][0] = MFMA_BF16(af, Bf1[0][c], c1a[ti][0], 0, 0, 0);
            c1a[ti][1] = MFMA_BF16(af, Bf1[1][c], c1a[ti][1], 0, 0, 0);
        }
    }
    LBAR();   // all image reads (both waves) done -> x2l may overlay ub

    // ---- conv1 epilogue: bias/relu -> x2l; ave1 -> vrow (owned rows); zero non-owned ----
    {
        const float bias0 = b1[col], bias1 = b1[col + 16];
        #pragma unroll
        for (int ti = 0; ti < 6; ++ti) {
            const int t = ti * 2 + p;
            if (t >= 11) break;
            #pragma unroll
            for (int r = 0; r < 4; ++r) {
                const int pr = t * 16 + quad * 4 + r;
                float v0 = c1a[ti][0][r] + bias0;
                float v1 = c1a[ti][1][r] + bias1;
                float s = v0 + v1;
                s += __shfl_xor(s, 1); s += __shfl_xor(s, 2);
                s += __shfl_xor(s, 4); s += __shfl_xor(s, 8);
                if (pr < 165) {
                    x2l[pr * 36 + col]      = f2bf(frelu(v0));
                    x2l[pr * 36 + col + 16] = f2bf(frelu(v1));
                    if (col == 0) vrow[pr] = s;
                }
            }
        }
        for (int i = lane; i < 165; i += 64)
            if (((i >> 4) & 1) != p) vrow[i] = 0.f;   // rows owned by the other wave
    }
    LBAR();

    // ---- conv2: M=35 (3 m-tiles), this wave's 32-oc half (2 n-tiles), K=288 (9 chunks) ----
    {
        int aoff[3];
        #pragma unroll
        for (int mt = 0; mt < 3; ++mt) {
            int pp = mt * 16 + col; pp = pp < 35 ? pp : 34;
            aoff[mt] = ((pp / 7) * 30 + (pp % 7) * 2) * 36 + quad * 8;
        }
        f32x4 a2[3][2] = {};
        #pragma unroll
        for (int c = 0; c < 9; ++c) {
            const int koff = ((c / 3) * 15 + (c % 3)) * 36;
            short8 A[3];
            #pragma unroll
            for (int mt = 0; mt < 3; ++mt) {
                const unsigned short* ap = x2l + aoff[mt] + koff;
                *(short4_t*)&A[mt]       = *(const short4_t*)ap;
                *((short4_t*)&A[mt] + 1) = *(const short4_t*)(ap + 4);
            }
            #pragma unroll
            for (int n = 0; n < 2; ++n) {
                short8 Bc = *(const short8*)(w2p + (size_t)(p * 32 + n * 16 + col) * 288 + c * 32 + quad * 8);
                #pragma unroll
                for (int mt = 0; mt < 3; ++mt)
                    a2[mt][n] = MFMA_BF16(A[mt], Bc, a2[mt][n], 0, 0, 0);
            }
        }
        float bv2[2];
        #pragma unroll
        for (int n = 0; n < 2; ++n) bv2[n] = b2[p * 32 + n * 16 + col];
        #pragma unroll
        for (int mt = 0; mt < 3; ++mt) {
            #pragma unroll
            for (int r = 0; r < 4; ++r) {
                const int pr = mt * 16 + quad * 4 + r;
                if (pr < 35) {
                    float s = 0.f;
                    #pragma unroll
                    for (int n = 0; n < 2; ++n) {
                        float v = a2[mt][n][r] + bv2[n];
                        s += v;
                        x4l[pr * 72 + p * 32 + n * 16 + col] = f2bf(frelu(v));
                    }
                    s += __shfl_xor(s, 1); s += __shfl_xor(s, 2);
                    s += __shfl_xor(s, 4); s += __shfl_xor(s, 8);
                    if (col == 0) vrow[165 + pr] = s;   // 32-oc partial; halves summed in reduce
                }
            }
        }
    }
    LBAR();

    // ---- conv3: M=15, this wave's 32-oc half (2 n-tiles), K=576 (18 chunks) ----
    {
        int pp = col < 15 ? col : 14;
        const int abase = ((pp / 5) * 7 + (pp % 5)) * 72;
        f32x4 a3[2] = {};
        #pragma unroll
        for (int cc = 0; cc < 9; ++cc) {
            const unsigned short* bp = x4l + abase + ((cc / 3) * 7 + (cc % 3)) * 72 + quad * 8;
            short8 af0 = *(const short8*)bp;          // ic 0..31  (16B aligned)
            short8 af1 = *(const short8*)(bp + 32);   // ic 32..63
            #pragma unroll
            for (int n = 0; n < 2; ++n) {
                const unsigned short* wb = w3p + (size_t)(p * 32 + n * 16 + col) * 576 + quad * 8;
                short8 B0 = *(const short8*)(wb + (2 * cc) * 32);
                short8 B1 = *(const short8*)(wb + (2 * cc + 1) * 32);
                a3[n] = MFMA_BF16(af0, B0, a3[n], 0, 0, 0);
                a3[n] = MFMA_BF16(af1, B1, a3[n], 0, 0, 0);
            }
        }
        float bv3[2];
        #pragma unroll
        for (int n = 0; n < 2; ++n) bv3[n] = b3[p * 32 + n * 16 + col];
        unsigned short* xout = x6 + (size_t)img * 960;
        #pragma unroll
        for (int r = 0; r < 4; ++r) {
            const int pr = quad * 4 + r;
            if (pr < 15) {
                float s = 0.f;
                #pragma unroll
                for (int n = 0; n < 2; ++n) {
                    float v = a3[n][r] + bv3[n];
                    s += v;
                    xout[pr * 64 + p * 32 + n * 16 + col] = f2bf(frelu(v));
                }
                s += __shfl_xor(s, 1); s += __shfl_xor(s, 2);
                s += __shfl_xor(s, 4); s += __shfl_xor(s, 8);
                if (col == 0) vrow[200 + pr] = s;     // 32-oc partial
            }
        }
    }
}

// ---------------- reduce: out[8192+row] = sum over 8192 virtual rows * scale ----------------
__global__ __launch_bounds__(256) void reduce_aves(const float* __restrict__ redbuf, float* __restrict__ out) {
    const int row = blockIdx.x;
    float s = 0.f;
    for (int i = threadIdx.x; i < 8192; i += 256) s += redbuf[(size_t)i * 216 + row];
    s += __shfl_down(s, 32); s += __shfl_down(s, 16); s += __shfl_down(s, 8);
    s += __shfl_down(s, 4);  s += __shfl_down(s, 2);  s += __shfl_down(s, 1);
    __shared__ float wsum[4];
    if ((threadIdx.x & 63) == 0) wsum[threadIdx.x >> 6] = s;
    __syncthreads();
    if (threadIdx.x == 0)
        out[8192 + row] = (wsum[0] + wsum[1] + wsum[2] + wsum[3]) * (row < 165 ? 0.03125f : 0.015625f);
}

// ---------------- fc4+fc5: out[b,2] += relu(x6@w4p^T + b4) @ w5^T ----------------
__global__ __launch_bounds__(256) void fc45_mfma(const unsigned short* __restrict__ x6,
                                                 const unsigned short* __restrict__ w4p, const float* __restrict__ b4,
                                                 const float* __restrict__ w5, float* __restrict__ out) {
    __shared__ float outl[32][2];
    const int tid = threadIdx.x;
    const int wave = tid >> 6, lane = tid & 63;
    const int col = lane & 15, quad = lane >> 4;
    if (tid < 64) outl[tid >> 1][tid & 1] = 0.f;
    const int m0 = blockIdx.x * 32;
    const int oc = blockIdx.y * 64 + wave * 16 + col;

    const unsigned short* brow  = w4p + (size_t)oc * 960 + quad * 8;
    const unsigned short* arow0 = x6 + (size_t)(m0 + col) * 960 + quad * 8;
    const unsigned short* arow1 = arow0 + 16 * 960;
    f32x4 acc0 = {}, acc1 = {};
    __syncthreads();
    #pragma unroll 6
    for (int c = 0; c < 30; ++c) {
        short8 Bf = *(const short8*)(brow + c * 32);
        short8 a0 = *(const short8*)(arow0 + c * 32);
        short8 a1 = *(const short8*)(arow1 + c * 32);
        acc0 = MFMA_BF16(a0, Bf, acc0, 0, 0, 0);
        acc1 = MFMA_BF16(a1, Bf, acc1, 0, 0, 0);
    }
    const float bb = b4[oc], u0 = w5[oc], u1 = w5[512 + oc];
    #pragma unroll
    for (int mi = 0; mi < 2; ++mi) {
        const f32x4 acc = mi ? acc1 : acc0;
        #pragma unroll
        for (int r = 0; r < 4; ++r) {
            float h = frelu(acc[r] + bb);
            float l0 = h * u0, l1 = h * u1;
            l0 += __shfl_xor(l0, 1); l0 += __shfl_xor(l0, 2); l0 += __shfl_xor(l0, 4); l0 += __shfl_xor(l0, 8);
            l1 += __shfl_xor(l1, 1); l1 += __shfl_xor(l1, 2); l1 += __shfl_xor(l1, 4); l1 += __shfl_xor(l1, 8);
            if (col == 0) {
                atomicAdd(&outl[mi * 16 + quad * 4 + r][0], l0);
                atomicAdd(&outl[mi * 16 + quad * 4 + r][1], l1);
            }
        }
    }
    __syncthreads();
    if (tid < 64) atomicAdd(&out[(m0 + (tid >> 1)) * 2 + (tid & 1)], outl[tid >> 1][tid & 1]);
}

extern "C" void kernel_launch(void* const* d_in, const int* in_sizes, int n_in,
                              void* d_out, int out_size, void* d_ws, size_t ws_size,
                              hipStream_t stream) {
    const float* x  = (const float*)d_in[0];
    const float* w1 = (const float*)d_in[1];
    const float* b1 = (const float*)d_in[2];
    const float* w2 = (const float*)d_in[3];
    const float* b2 = (const float*)d_in[4];
    const float* w3 = (const float*)d_in[5];
    const float* b3 = (const float*)d_in[6];
    const float* w4 = (const float*)d_in[7];
    const float* b4 = (const float*)d_in[8];
    const float* w5 = (const float*)d_in[9];
    const float* b5 = (const float*)d_in[10];
    float* out = (float*)d_out;

    unsigned short* ws = (unsigned short*)d_ws;
    unsigned short* x6  = ws;                      // 3,932,160 ushort
    unsigned short* w1p = ws + 3932160;            //      6,144
    unsigned short* w2p = ws + 3938304;            //     18,432
    unsigned short* w3p = ws + 3956736;            //     36,864
    unsigned short* w4p = ws + 3993600;            //    491,520
    float* redbuf = (float*)((char*)d_ws + 8970240); // 8192*216 floats = 7,077,888 B

    prep_kernel<<<2193, 256, 0, stream>>>(w1, w2, w3, w4, b5, w1p, w2p, w3p, w4p, out);
    fused_convs<<<2048, 256, 0, stream>>>(x, w1p, b1, w2p, b2, w3p, b3, x6, redbuf);
    reduce_aves<<<215, 256, 0, stream>>>(redbuf, out);
    fc45_mfma<<<dim3(128, 8), 256, 0, stream>>>(x6, w4p, b4, w5, out);
}